// Round 2
// baseline (253.944 us; speedup 1.0000x reference)
//
#include <hip/hip_runtime.h>

#define BLK 256
#define QPT 16       // query points per thread
#define SLICES 32    // target slices per direction
#define TT 256       // targets per slice tile (= 8192 / SLICES)

__global__ __launch_bounds__(256) void init_mins(unsigned int* mins, int n) {
    int i = blockIdx.x * 256 + threadIdx.x;
    if (i < n) mins[i] = 0x7f800000u;  // +inf bit pattern
}

// dir 0: queries = pred (pc_p), targets = gt  -> minP region
// dir 1: queries = gt  (pc_gt), targets = pred -> minG region
__global__ __launch_bounds__(BLK, 4) void chamfer_min(
    const float* __restrict__ gt, const float* __restrict__ pp,
    unsigned int* __restrict__ minP, unsigned int* __restrict__ minG,
    int M, int N)
{
    const int dir = (blockIdx.z >= SLICES) ? 1 : 0;
    const int s   = blockIdx.z - dir * SLICES;
    const float* __restrict__ Q = dir ? gt : pp;
    const float* __restrict__ T = dir ? pp : gt;
    unsigned int* mins = dir ? minG : minP;
    const int NQ = dir ? N : M;
    const int NT = dir ? M : N;
    const int b  = blockIdx.y;

    // stage target slice into LDS as (-2x, -2y, -2z, |t|^2)
    __shared__ float4 sT[TT];
    {
        const float* tb = T + ((size_t)b * NT + (size_t)s * TT) * 3;
        for (int j = threadIdx.x; j < TT; j += BLK) {
            float x = tb[3 * j], y = tb[3 * j + 1], z = tb[3 * j + 2];
            sT[j] = make_float4(-2.f * x, -2.f * y, -2.f * z,
                                x * x + y * y + z * z);
        }
    }
    __syncthreads();

    const int q0 = blockIdx.x * (BLK * QPT) + threadIdx.x * QPT;
    if (q0 >= NQ) return;

    // load 16 query points (48 floats = 12 aligned float4 loads)
    const float* qb = Q + ((size_t)b * NQ + q0) * 3;
    float buf[3 * QPT];
#pragma unroll
    for (int i = 0; i < (3 * QPT) / 4; ++i) {
        float4 v = ((const float4*)qb)[i];
        buf[4 * i + 0] = v.x; buf[4 * i + 1] = v.y;
        buf[4 * i + 2] = v.z; buf[4 * i + 3] = v.w;
    }
    float qx[QPT], qy[QPT], qz[QPT], best[QPT];
#pragma unroll
    for (int q = 0; q < QPT; ++q) {
        qx[q] = buf[3 * q]; qy[q] = buf[3 * q + 1]; qz[q] = buf[3 * q + 2];
        best[q] = 3.0e38f;
    }

    // min over targets of (|t|^2 - 2 q.t); add |q|^2 back at the end.
    // Process columns in pairs -> v_min3_f32; prefetch next pair.
    float4 ta = sT[0], tb2 = sT[1];
    for (int j = 0; j < TT; j += 2) {
        const int jn = (j + 2) & (TT - 1);
        float4 na = sT[jn], nb = sT[jn + 1];
#pragma unroll
        for (int q = 0; q < QPT; ++q) {
            float A = __builtin_fmaf(qz[q], ta.z, ta.w);
            float B = __builtin_fmaf(qz[q], tb2.z, tb2.w);
            A = __builtin_fmaf(qy[q], ta.y, A);
            B = __builtin_fmaf(qy[q], tb2.y, B);
            A = __builtin_fmaf(qx[q], ta.x, A);
            B = __builtin_fmaf(qx[q], tb2.x, B);
            best[q] = fminf(fminf(best[q], A), B);  // -> v_min3_f32
        }
        ta = na; tb2 = nb;
    }

    unsigned int* mp = mins + (size_t)b * NQ + q0;
#pragma unroll
    for (int q = 0; q < QPT; ++q) {
        float aq = __builtin_fmaf(qx[q], qx[q],
                   __builtin_fmaf(qy[q], qy[q], qz[q] * qz[q]));
        float d = fmaxf(best[q] + aq, 0.f);  // clamp tiny negative cancellation
        unsigned int u = __float_as_uint(d);
        if (u < mp[q]) atomicMin(&mp[q], u);  // precheck: skip guaranteed losers
    }
}

__device__ double block_reduce_d(double v) {
    __shared__ double red[4];
    for (int o = 32; o > 0; o >>= 1) v += __shfl_down(v, o);
    int lane = threadIdx.x & 63, w = threadIdx.x >> 6;
    if (lane == 0) red[w] = v;
    __syncthreads();
    if (threadIdx.x == 0) v = red[0] + red[1] + red[2] + red[3];
    return v;
}

__global__ __launch_bounds__(256) void reduce1(const unsigned int* __restrict__ mins,
                                               double* __restrict__ partials,
                                               int EM, int E, double wP, double wG) {
    double acc = 0.0;
    for (int i = blockIdx.x * 256 + threadIdx.x; i < E; i += 256 * 256)
        acc += (double)__uint_as_float(mins[i]) * (i < EM ? wP : wG);
    double s = block_reduce_d(acc);
    if (threadIdx.x == 0) partials[blockIdx.x] = s;
}

__global__ __launch_bounds__(256) void reduce2(const double* __restrict__ partials,
                                               float* __restrict__ out) {
    double s = block_reduce_d(partials[threadIdx.x]);
    if (threadIdx.x == 0) out[0] = (float)s;
}

extern "C" void kernel_launch(void* const* d_in, const int* in_sizes, int n_in,
                              void* d_out, int out_size, void* d_ws, size_t ws_size,
                              hipStream_t stream) {
    const float* gt = (const float*)d_in[0];  // pc_gt (B,N,3)
    const float* pp = (const float*)d_in[1];  // pc_p  (B,M,3)
    const int B = 8;
    const int N = in_sizes[0] / (B * 3);
    const int M = in_sizes[1] / (B * 3);
    const int EM = B * M, EN = B * N, E = EM + EN;

    unsigned int* mins = (unsigned int*)d_ws;            // E uints (minP | minG)
    double* partials = (double*)((char*)d_ws + (size_t)E * 4);  // 256 doubles
    float* out = (float*)d_out;

    init_mins<<<(E + 255) / 256, 256, 0, stream>>>(mins, E);

    const int NQmax = (M > N) ? M : N;
    dim3 grid((NQmax + BLK * QPT - 1) / (BLK * QPT), B, 2 * SLICES);
    chamfer_min<<<grid, BLK, 0, stream>>>(gt, pp, mins, mins + EM, M, N);

    reduce1<<<256, 256, 0, stream>>>(mins, partials, EM, E,
                                     1.0 / (double)EM, 1.0 / (double)EN);
    reduce2<<<1, 256, 0, stream>>>(partials, out);
}

// Round 3
// 163.988 us; speedup vs baseline: 1.5486x; 1.5486x over previous
//
#include <hip/hip_runtime.h>

#define BLK 256
#define QPT 16       // query points per thread
#define SLICES 16    // target slices per direction
#define TT 512       // targets per slice tile (= 8192 / SLICES)

__global__ __launch_bounds__(256) void init_mins(unsigned int* mins, int n) {
    int i = blockIdx.x * 256 + threadIdx.x;
    if (i < n) mins[i] = 0x7f800000u;  // +inf bit pattern
}

// dir 0: queries = pred (pc_p), targets = gt  -> minP region
// dir 1: queries = gt  (pc_gt), targets = pred -> minG region
__global__ __launch_bounds__(BLK) void chamfer_min(
    const float* __restrict__ gt, const float* __restrict__ pp,
    unsigned int* __restrict__ minP, unsigned int* __restrict__ minG,
    int M, int N)
{
    const int dir = (blockIdx.z >= SLICES) ? 1 : 0;
    const int s   = blockIdx.z - dir * SLICES;
    const float* __restrict__ Q = dir ? gt : pp;
    const float* __restrict__ T = dir ? pp : gt;
    unsigned int* mins = dir ? minG : minP;
    const int NQ = dir ? N : M;
    const int NT = dir ? M : N;
    const int b  = blockIdx.y;

    // stage target slice into LDS as (-2x, -2y, -2z, |t|^2)
    __shared__ float4 sT[TT];
    {
        const float* tb = T + ((size_t)b * NT + (size_t)s * TT) * 3;
        for (int j = threadIdx.x; j < TT; j += BLK) {
            float x = tb[3 * j], y = tb[3 * j + 1], z = tb[3 * j + 2];
            sT[j] = make_float4(-2.f * x, -2.f * y, -2.f * z,
                                x * x + y * y + z * z);
        }
    }
    __syncthreads();

    const int q0 = blockIdx.x * (BLK * QPT) + threadIdx.x * QPT;
    if (q0 >= NQ) return;

    // load 16 query points (48 floats = 12 aligned float4 loads),
    // direct register assignment — no intermediate array (spill-safe).
    const float* qb = Q + ((size_t)b * NQ + q0) * 3;
    const float4* qv = (const float4*)qb;
    float4 f0 = qv[0], f1 = qv[1], f2 = qv[2],  f3 = qv[3],  f4 = qv[4],  f5 = qv[5];
    float4 f6 = qv[6], f7 = qv[7], f8 = qv[8],  f9 = qv[9],  fa = qv[10], fb = qv[11];

    float qx[QPT], qy[QPT], qz[QPT], best[QPT];
    qx[0]  = f0.x; qy[0]  = f0.y; qz[0]  = f0.z;
    qx[1]  = f0.w; qy[1]  = f1.x; qz[1]  = f1.y;
    qx[2]  = f1.z; qy[2]  = f1.w; qz[2]  = f2.x;
    qx[3]  = f2.y; qy[3]  = f2.z; qz[3]  = f2.w;
    qx[4]  = f3.x; qy[4]  = f3.y; qz[4]  = f3.z;
    qx[5]  = f3.w; qy[5]  = f4.x; qz[5]  = f4.y;
    qx[6]  = f4.z; qy[6]  = f4.w; qz[6]  = f5.x;
    qx[7]  = f5.y; qy[7]  = f5.z; qz[7]  = f5.w;
    qx[8]  = f6.x; qy[8]  = f6.y; qz[8]  = f6.z;
    qx[9]  = f6.w; qy[9]  = f7.x; qz[9]  = f7.y;
    qx[10] = f7.z; qy[10] = f7.w; qz[10] = f8.x;
    qx[11] = f8.y; qy[11] = f8.z; qz[11] = f8.w;
    qx[12] = f9.x; qy[12] = f9.y; qz[12] = f9.z;
    qx[13] = f9.w; qy[13] = fa.x; qz[13] = fa.y;
    qx[14] = fa.z; qy[14] = fa.w; qz[14] = fb.x;
    qx[15] = fb.y; qy[15] = fb.z; qz[15] = fb.w;
#pragma unroll
    for (int q = 0; q < QPT; ++q) best[q] = 3.0e38f;

    // min over targets of (|t|^2 - 2 q.t); add |q|^2 back at the end.
    // Column pairs -> fminf(fminf(best,A),B) fuses to v_min3_f32.
#pragma unroll 2
    for (int j = 0; j < TT; j += 2) {
        float4 ca = sT[j];
        float4 cb = sT[j + 1];
#pragma unroll
        for (int q = 0; q < QPT; ++q) {
            float A = __builtin_fmaf(qz[q], ca.z, ca.w);
            float B = __builtin_fmaf(qz[q], cb.z, cb.w);
            A = __builtin_fmaf(qy[q], ca.y, A);
            B = __builtin_fmaf(qy[q], cb.y, B);
            A = __builtin_fmaf(qx[q], ca.x, A);
            B = __builtin_fmaf(qx[q], cb.x, B);
            best[q] = fminf(fminf(best[q], A), B);
        }
    }

    unsigned int* mp = mins + (size_t)b * NQ + q0;
#pragma unroll
    for (int q = 0; q < QPT; ++q) {
        float aq = __builtin_fmaf(qx[q], qx[q],
                   __builtin_fmaf(qy[q], qy[q], qz[q] * qz[q]));
        float d = fmaxf(best[q] + aq, 0.f);  // clamp tiny negative cancellation
        atomicMin(&mp[q], __float_as_uint(d));
    }
}

__device__ double block_reduce_d(double v) {
    __shared__ double red[4];
    for (int o = 32; o > 0; o >>= 1) v += __shfl_down(v, o);
    int lane = threadIdx.x & 63, w = threadIdx.x >> 6;
    if (lane == 0) red[w] = v;
    __syncthreads();
    if (threadIdx.x == 0) v = red[0] + red[1] + red[2] + red[3];
    return v;
}

__global__ __launch_bounds__(256) void reduce1(const unsigned int* __restrict__ mins,
                                               double* __restrict__ partials,
                                               int EM, int E, double wP, double wG) {
    double acc = 0.0;
    for (int i = blockIdx.x * 256 + threadIdx.x; i < E; i += 256 * 256)
        acc += (double)__uint_as_float(mins[i]) * (i < EM ? wP : wG);
    double s = block_reduce_d(acc);
    if (threadIdx.x == 0) partials[blockIdx.x] = s;
}

__global__ __launch_bounds__(256) void reduce2(const double* __restrict__ partials,
                                               float* __restrict__ out) {
    double s = block_reduce_d(partials[threadIdx.x]);
    if (threadIdx.x == 0) out[0] = (float)s;
}

extern "C" void kernel_launch(void* const* d_in, const int* in_sizes, int n_in,
                              void* d_out, int out_size, void* d_ws, size_t ws_size,
                              hipStream_t stream) {
    const float* gt = (const float*)d_in[0];  // pc_gt (B,N,3)
    const float* pp = (const float*)d_in[1];  // pc_p  (B,M,3)
    const int B = 8;
    const int N = in_sizes[0] / (B * 3);
    const int M = in_sizes[1] / (B * 3);
    const int EM = B * M, EN = B * N, E = EM + EN;

    unsigned int* mins = (unsigned int*)d_ws;            // E uints (minP | minG)
    double* partials = (double*)((char*)d_ws + (size_t)E * 4);  // 256 doubles
    float* out = (float*)d_out;

    init_mins<<<(E + 255) / 256, 256, 0, stream>>>(mins, E);

    const int NQmax = (M > N) ? M : N;
    dim3 grid((NQmax + BLK * QPT - 1) / (BLK * QPT), B, 2 * SLICES);
    chamfer_min<<<grid, BLK, 0, stream>>>(gt, pp, mins, mins + EM, M, N);

    reduce1<<<256, 256, 0, stream>>>(mins, partials, EM, E,
                                     1.0 / (double)EM, 1.0 / (double)EN);
    reduce2<<<1, 256, 0, stream>>>(partials, out);
}

// Round 4
// 88.198 us; speedup vs baseline: 2.8793x; 1.8593x over previous
//
#include <hip/hip_runtime.h>

#define BLK 256
#define QPT 16       // query points per thread (named scalars, no arrays!)
#define SLICES 16    // target slices per direction
#define TT 512       // targets per slice tile (= 8192 / SLICES)

#define Q_ITER(F) F(0) F(1) F(2) F(3) F(4) F(5) F(6) F(7) \
                  F(8) F(9) F(10) F(11) F(12) F(13) F(14) F(15)

__global__ __launch_bounds__(256) void init_mins(unsigned int* mins, int n) {
    int i = blockIdx.x * 256 + threadIdx.x;
    if (i < n) mins[i] = 0x7f800000u;  // +inf
}

// dir 0: queries = pred (pc_p), targets = gt  -> P region
// dir 1: queries = gt  (pc_gt), targets = pred -> G region
template <bool USE_ATOMIC>
__global__ __launch_bounds__(BLK) void chamfer_min(
    const float* __restrict__ gt, const float* __restrict__ pp,
    unsigned int* __restrict__ minP, unsigned int* __restrict__ minG,
    float* __restrict__ dP, float* __restrict__ dG,
    int M, int N)
{
    const int dir = (blockIdx.z >= SLICES) ? 1 : 0;
    const int s   = blockIdx.z - dir * SLICES;
    const float* __restrict__ Q = dir ? gt : pp;
    const float* __restrict__ T = dir ? pp : gt;
    const int NQ = dir ? N : M;
    const int NT = dir ? M : N;
    const int b  = blockIdx.y;

    // stage target slice into LDS as (-2x, -2y, -2z, |t|^2)
    __shared__ float4 sT[TT];
    {
        const float* tb = T + ((size_t)b * NT + (size_t)s * TT) * 3;
        for (int j = threadIdx.x; j < TT; j += BLK) {
            float x = tb[3 * j], y = tb[3 * j + 1], z = tb[3 * j + 2];
            sT[j] = make_float4(-2.f * x, -2.f * y, -2.f * z,
                                x * x + y * y + z * z);
        }
    }
    __syncthreads();

    const int q0 = blockIdx.x * (BLK * QPT) + threadIdx.x * QPT;
    if (q0 >= NQ) return;

    // 16 query points = 48 floats = 12 aligned float4 loads -> named scalars
    const float4* qv = (const float4*)(Q + ((size_t)b * NQ + q0) * 3);
    float4 f0 = qv[0], f1 = qv[1], f2 = qv[2],  f3 = qv[3],  f4 = qv[4],  f5 = qv[5];
    float4 f6 = qv[6], f7 = qv[7], f8 = qv[8],  f9 = qv[9],  fa = qv[10], fb = qv[11];

#define DECLQ(i) float qx##i, qy##i, qz##i, bb##i = 3.0e38f;
    Q_ITER(DECLQ)
#undef DECLQ
    qx0  = f0.x; qy0  = f0.y; qz0  = f0.z;
    qx1  = f0.w; qy1  = f1.x; qz1  = f1.y;
    qx2  = f1.z; qy2  = f1.w; qz2  = f2.x;
    qx3  = f2.y; qy3  = f2.z; qz3  = f2.w;
    qx4  = f3.x; qy4  = f3.y; qz4  = f3.z;
    qx5  = f3.w; qy5  = f4.x; qz5  = f4.y;
    qx6  = f4.z; qy6  = f4.w; qz6  = f5.x;
    qx7  = f5.y; qy7  = f5.z; qz7  = f5.w;
    qx8  = f6.x; qy8  = f6.y; qz8  = f6.z;
    qx9  = f6.w; qy9  = f7.x; qz9  = f7.y;
    qx10 = f7.z; qy10 = f7.w; qz10 = f8.x;
    qx11 = f8.y; qy11 = f8.z; qz11 = f8.w;
    qx12 = f9.x; qy12 = f9.y; qz12 = f9.z;
    qx13 = f9.w; qy13 = fa.x; qz13 = fa.y;
    qx14 = fa.z; qy14 = fa.w; qz14 = fb.x;
    qx15 = fb.y; qy15 = fb.z; qz15 = fb.w;

    // min over targets of (|t|^2 - 2 q.t); add |q|^2 back at the end.
    // Column pairs: fminf(fminf(bb,A),B) -> v_min3_f32.
    for (int j = 0; j < TT; j += 2) {
        float4 ca = sT[j];
        float4 cb = sT[j + 1];
#define STEP(i) { \
        float A  = __builtin_fmaf(qz##i, ca.z, ca.w); \
        float Bv = __builtin_fmaf(qz##i, cb.z, cb.w); \
        A  = __builtin_fmaf(qy##i, ca.y, A); \
        Bv = __builtin_fmaf(qy##i, cb.y, Bv); \
        A  = __builtin_fmaf(qx##i, ca.x, A); \
        Bv = __builtin_fmaf(qx##i, cb.x, Bv); \
        bb##i = fminf(fminf(bb##i, A), Bv); }
        Q_ITER(STEP)
#undef STEP
    }

    unsigned int* mp = (dir ? minG : minP) + (size_t)b * NQ + q0;
    float* op = (dir ? dG : dP) + (size_t)s * ((size_t)gridDim.y * NQ)
                                + (size_t)b * NQ + q0;
#define FIN(i) { \
        float aq = __builtin_fmaf(qx##i, qx##i, \
                   __builtin_fmaf(qy##i, qy##i, qz##i * qz##i)); \
        float d = fmaxf(bb##i + aq, 0.f); \
        if (USE_ATOMIC) atomicMin(&mp[i], __float_as_uint(d)); \
        else op[i] = d; }
    Q_ITER(FIN)
#undef FIN
}

__device__ double block_reduce_d(double v) {
    __shared__ double red[4];
    for (int o = 32; o > 0; o >>= 1) v += __shfl_down(v, o);
    int lane = threadIdx.x & 63, w = threadIdx.x >> 6;
    if (lane == 0) red[w] = v;
    __syncthreads();
    if (threadIdx.x == 0) v = red[0] + red[1] + red[2] + red[3];
    return v;
}

// fold SLICES per-slice mins + weighted sum
__global__ __launch_bounds__(256) void reduce1_slices(
    const float* __restrict__ dP, const float* __restrict__ dG,
    double* __restrict__ partials, int EM, int EN, double wP, double wG) {
    const int E = EM + EN;
    double acc = 0.0;
    for (int i = blockIdx.x * 256 + threadIdx.x; i < E; i += 256 * 256) {
        const float* base; int stride; double w;
        if (i < EM) { base = dP + i;        stride = EM; w = wP; }
        else        { base = dG + (i - EM); stride = EN; w = wG; }
        float m = base[0];
#pragma unroll
        for (int s = 1; s < SLICES; ++s) m = fminf(m, base[(size_t)s * stride]);
        acc += (double)m * w;
    }
    double s = block_reduce_d(acc);
    if (threadIdx.x == 0) partials[blockIdx.x] = s;
}

__global__ __launch_bounds__(256) void reduce1_atomic(
    const unsigned int* __restrict__ mins, double* __restrict__ partials,
    int EM, int E, double wP, double wG) {
    double acc = 0.0;
    for (int i = blockIdx.x * 256 + threadIdx.x; i < E; i += 256 * 256)
        acc += (double)__uint_as_float(mins[i]) * (i < EM ? wP : wG);
    double s = block_reduce_d(acc);
    if (threadIdx.x == 0) partials[blockIdx.x] = s;
}

__global__ __launch_bounds__(256) void reduce2(const double* __restrict__ partials,
                                               float* __restrict__ out) {
    double s = block_reduce_d(partials[threadIdx.x]);
    if (threadIdx.x == 0) out[0] = (float)s;
}

extern "C" void kernel_launch(void* const* d_in, const int* in_sizes, int n_in,
                              void* d_out, int out_size, void* d_ws, size_t ws_size,
                              hipStream_t stream) {
    const float* gt = (const float*)d_in[0];  // pc_gt (B,N,3)
    const float* pp = (const float*)d_in[1];  // pc_p  (B,M,3)
    const int B = 8;
    const int N = in_sizes[0] / (B * 3);
    const int M = in_sizes[1] / (B * 3);
    const int EM = B * M, EN = B * N, E = EM + EN;
    float* out = (float*)d_out;

    const int NQmax = (M > N) ? M : N;
    dim3 grid((NQmax + BLK * QPT - 1) / (BLK * QPT), B, 2 * SLICES);

    const size_t needNA = (size_t)SLICES * E * 4 + 256 * 8;
    if (ws_size >= needNA) {
        // no-atomic path: per-slice buffers + fused slice-min reduction
        float* dP = (float*)d_ws;                       // SLICES x EM
        float* dG = dP + (size_t)SLICES * EM;           // SLICES x EN
        double* partials = (double*)((char*)d_ws + (size_t)SLICES * E * 4);
        chamfer_min<false><<<grid, BLK, 0, stream>>>(gt, pp, nullptr, nullptr,
                                                     dP, dG, M, N);
        reduce1_slices<<<256, 256, 0, stream>>>(dP, dG, partials, EM, EN,
                                                1.0 / (double)EM, 1.0 / (double)EN);
        reduce2<<<1, 256, 0, stream>>>(partials, out);
    } else {
        // fallback: atomic-min path (round-1 proven)
        unsigned int* mins = (unsigned int*)d_ws;
        double* partials = (double*)((char*)d_ws + (size_t)E * 4);
        init_mins<<<(E + 255) / 256, 256, 0, stream>>>(mins, E);
        chamfer_min<true><<<grid, BLK, 0, stream>>>(gt, pp, mins, mins + EM,
                                                    nullptr, nullptr, M, N);
        reduce1_atomic<<<256, 256, 0, stream>>>(mins, partials, EM, E,
                                                1.0 / (double)EM, 1.0 / (double)EN);
        reduce2<<<1, 256, 0, stream>>>(partials, out);
    }
}